// Round 6
// baseline (204.887 us; speedup 1.0000x reference)
//
#include <hip/hip_runtime.h>
#include <math.h>

// YOLO loss: pred/target (BATCH,7,7,30) f32, choice (BATCH,7,7) i32
// -> 4 scalars (loc, cls, obj, noobj).
// Round-15: r7 structure (best, ~50us main / 193.9 total) with ONE change:
// staging loads become inline-asm buffer_load_dwordx4 "offen nt sc1"
// (SRSRC path). Theory: the ~3.9 TB/s read cap (robust across r7/r11/
// r12/r13/r14 structures) is L2-ALLOCATION rate; nt already bypasses L1
// allocate (75->50us win), sc1 requests stream/no-allocate at L2 too.
// Explicit s_waitcnt vmcnt(0) before the LDS-store consumption point
// (inline-asm loads are invisible to compiler waitcnt tracking).
// If neutral: the cap is fabric/HBM-read-port -> revert r7, declare.
// Loaded values identical -> outputs bitwise identical to r7 baseline.

typedef float vf4 __attribute__((ext_vector_type(4)));   // 128-bit load payload
typedef int   v4i __attribute__((ext_vector_type(4)));   // SRSRC in SGPR quad

constexpr int NCH = 30;    // 5*B + C
constexpr int CC  = 20;    // classes
constexpr int ROW = 8;     // floats per block's partial row (32 B)
constexpr int T   = 256;   // threads per block (4 waves)
constexpr int CPB = 128;   // cells per chunk
constexpr int NF4 = CPB * NCH * 2 / 4;  // 1920 vf4 per chunk (pred+target)
constexpr int HF4 = NF4 / 2;            // 960: pred/target boundary
constexpr int GRID = 1280; // 5 blocks/CU * 256 CU

__device__ __forceinline__ v4i make_srsrc(const void* p, unsigned bytes) {
    unsigned long long a = (unsigned long long)p;
    v4i r;
    r.x = (int)(a & 0xFFFFFFFFull);
    r.y = (int)(a >> 32);          // stride=0, pointer < 2^48
    r.z = (int)bytes;              // num_records: OOB reads return 0
    r.w = 0x00020000;              // raw untyped dword access
    return r;
}

__device__ __forceinline__ vf4 bload_nt_sc1(v4i srsrc, int voff) {
    vf4 out;
    asm volatile("buffer_load_dwordx4 %0, %1, %2, 0 offen nt sc1"
                 : "=v"(out) : "v"(voff), "s"(srsrc) : "memory");
    return out;
}

__device__ __forceinline__ void issue_chunk(
    const float* __restrict__ pred, const float* __restrict__ target,
    const int* __restrict__ choice, v4i srP, v4i srT,
    int cc, int ncells, int tid, vf4 (&r)[8], int& ci)
{
    long long base = (long long)cc * CPB;
    if (base + CPB <= (long long)ncells) {
        int cb = (int)(base * NCH * 4);     // chunk byte offset (<97 MB, fits int)
        #pragma unroll
        for (int j = 0; j < 8; ++j) {
            int k = j * T + tid;            // guards wave-uniform (T mult of 64)
            if (k < NF4)
                r[j] = (k < HF4) ? bload_nt_sc1(srP, cb + k * 16)
                                 : bload_nt_sc1(srT, cb + (k - HF4) * 16);
        }
    } else {
        int nfl = (int)(ncells - base) * NCH;   // valid floats per array
        const float* Pf = pred + base * NCH;
        const float* Tf = target + base * NCH;
        #pragma unroll
        for (int j = 0; j < 8; ++j) {
            int k = j * T + tid;
            vf4 v = (vf4)(0.f, 0.f, 0.f, 0.f);
            if (k < NF4) {
                int kk = (k < HF4) ? k : k - HF4;
                const float* src = (k < HF4) ? Pf : Tf;
                int b = 4 * kk;
                if (b + 0 < nfl) v.x = src[b + 0];
                if (b + 1 < nfl) v.y = src[b + 1];
                if (b + 2 < nfl) v.z = src[b + 2];
                if (b + 3 < nfl) v.w = src[b + 3];
            }
            r[j] = v;
        }
    }
    if (tid < CPB) {
        long long ce = base + tid;
        ci = (ce < (long long)ncells) ? __builtin_nontemporal_load(&choice[ce]) : 0;
    }
}

__global__ __launch_bounds__(T) void yolo_main(
    const float* __restrict__ pred, const float* __restrict__ target,
    const int* __restrict__ choice, float* __restrict__ ws,
    int ncells, int nchunks)
{
    __shared__ float sbuf[2 * CPB * NCH];   // 30720 B: [pred chunk][target chunk]
    const int tid = threadIdx.x;

    const v4i srP = make_srsrc(pred,   (unsigned)((long long)ncells * NCH * 4));
    const v4i srT = make_srsrc(target, (unsigned)((long long)ncells * NCH * 4));

    float a_loc = 0.f, a_ce = 0.f, a_obj = 0.f, a_no = 0.f;
    float a_nob = 0.f, a_nno = 0.f;

    vf4 r[8];
    int ci = 0;
    int c = blockIdx.x;
    if (c < nchunks) issue_chunk(pred, target, choice, srP, srT, c, ncells, tid, r, ci);

    for (; c < nchunks; c += GRID) {
        __syncthreads();                    // prev compute done reading sbuf
        // inline-asm loads are untracked by compiler waitcnt: drain before use
        asm volatile("s_waitcnt vmcnt(0)" ::: "memory");
        #pragma unroll
        for (int j = 0; j < 8; ++j) {
            int k = j * T + tid;
            if (k < NF4) *(vf4*)&sbuf[k * 4] = r[j];
        }
        int myc = ci;
        __syncthreads();                    // chunk c visible

        int cn = c + GRID;                  // PREFETCH next chunk before compute
        if (cn < nchunks)
            issue_chunk(pred, target, choice, srP, srT, cn, ncells, tid, r, ci);

        if (tid < CPB && (long long)c * CPB + tid < ncells) {
            const float* sp  = &sbuf[tid * NCH];
            const float* stt = &sbuf[CPB * NCH + tid * NCH];
            float p[NCH], t[NCH];
            #pragma unroll
            for (int i = 0; i < NCH / 2; ++i) {
                float2 v = *(const float2*)&sp[2 * i];  p[2*i] = v.x; p[2*i+1] = v.y;
            }
            #pragma unroll
            for (int i = 0; i < NCH / 2; ++i) {
                float2 w = *(const float2*)&stt[2 * i]; t[2*i] = w.x; t[2*i+1] = w.y;
            }
            bool csel = myc != 0;

            float tconf = t[4];
            bool  obj = tconf > 0.0f;
            float m = obj ? 1.0f : 0.0f;

            float pxy0 = csel ? p[0] : p[5];
            float pxy1 = csel ? p[1] : p[6];
            float pwh0 = csel ? p[2] : p[7];
            float pwh1 = csel ? p[3] : p[8];
            float pobj = csel ? p[4] : p[9];
            float txy0 = csel ? t[0] : t[5];
            float txy1 = csel ? t[1] : t[6];
            float twh0 = csel ? t[2] : t[7];
            float twh1 = csel ? t[3] : t[8];
            if (!obj) { twh0 = 1.0f; twh1 = 1.0f; }
            float tobj = csel ? tconf : t[9];

            float dx = pxy0 - txy0, dy = pxy1 - txy1;
            float dw = pwh0 - sqrtf(twh0), dh = pwh1 - sqrtf(twh1);
            a_loc += m * (0.5f * (dx*dx + dy*dy) + 0.5f * (dw*dw + dh*dh));

            float dob = pobj - tobj;
            a_obj += m * dob * dob;

            float nm = (tconf == 0.0f) ? 1.0f : 0.0f;
            float d4 = p[4] - tconf, d9 = p[9] - t[9];
            a_no += nm * (d4 * d4 + d9 * d9);

            a_nob += m;
            a_nno += nm;

            int   tcls  = 0;
            float tbest = t[10];
            #pragma unroll
            for (int i = 1; i < CC; ++i) {
                float v = t[10 + i];
                if (v > tbest) { tbest = v; tcls = i; }
            }
            float mx = p[10];
            #pragma unroll
            for (int i = 1; i < CC; ++i) mx = fmaxf(mx, p[10 + i]);
            float e[CC];
            float Z = 0.f;
            #pragma unroll
            for (int i = 0; i < CC; ++i) { e[i] = __expf(p[10+i] - mx); Z += e[i]; }
            float rZ = 1.0f / Z;
            float Z2 = 0.f, sm_t = 0.f;
            #pragma unroll
            for (int i = 0; i < CC; ++i) {
                float sm = e[i] * rZ;          // in (0,1] -> exp safe
                Z2 += __expf(sm);
                if (i == tcls) sm_t = sm;
            }
            a_ce += m * (__logf(Z2) - sm_t);
        }
    }

    // wave(64) shuffle reduction of the 6 accumulators
    #pragma unroll
    for (int off = 32; off > 0; off >>= 1) {
        a_loc += __shfl_down(a_loc, off);
        a_ce  += __shfl_down(a_ce,  off);
        a_obj += __shfl_down(a_obj, off);
        a_no  += __shfl_down(a_no,  off);
        a_nob += __shfl_down(a_nob, off);
        a_nno += __shfl_down(a_nno, off);
    }

    __shared__ float red[4][6];
    int wave = tid >> 6;
    int lane = tid & 63;
    if (lane == 0) {
        red[wave][0] = a_loc; red[wave][1] = a_ce;  red[wave][2] = a_obj;
        red[wave][3] = a_no;  red[wave][4] = a_nob; red[wave][5] = a_nno;
    }
    __syncthreads();
    if (tid < 6) {   // NO atomics: private row per block
        float v = red[0][tid] + red[1][tid] + red[2][tid] + red[3][tid];
        ws[(size_t)blockIdx.x * ROW + tid] = v;
    }
}

__global__ __launch_bounds__(256) void yolo_reduce(
    const float* __restrict__ ws, float* __restrict__ out, int nb)
{
    float s[6] = {0.f, 0.f, 0.f, 0.f, 0.f, 0.f};
    for (int b = threadIdx.x; b < nb; b += 256) {
        #pragma unroll
        for (int j = 0; j < 6; ++j) s[j] += ws[(size_t)b * ROW + j];
    }
    #pragma unroll
    for (int off = 32; off > 0; off >>= 1) {
        #pragma unroll
        for (int j = 0; j < 6; ++j) s[j] += __shfl_down(s[j], off);
    }
    __shared__ float red[4][6];
    int wave = threadIdx.x >> 6;
    int lane = threadIdx.x & 63;
    if (lane == 0) {
        #pragma unroll
        for (int j = 0; j < 6; ++j) red[wave][j] = s[j];
    }
    __syncthreads();
    if (threadIdx.x == 0) {
        float t[6];
        #pragma unroll
        for (int j = 0; j < 6; ++j)
            t[j] = red[0][j] + red[1][j] + red[2][j] + red[3][j];
        out[0] = 5.0f * t[0];                     // loc_loss  (L_COORD = 5)
        out[1] = t[1] / fmaxf(t[4], 1.0f);        // cls_loss
        out[2] = t[2];                            // obj_loss
        out[3] = 0.5f * t[3] / fmaxf(t[5], 1.0f); // noobj_loss (L_NOOBJ = 0.5)
    }
}

extern "C" void kernel_launch(void* const* d_in, const int* in_sizes, int n_in,
                              void* d_out, int out_size, void* d_ws, size_t ws_size,
                              hipStream_t stream) {
    const float* pred   = (const float*)d_in[0];
    const float* target = (const float*)d_in[1];
    const int*   choice = (const int*)d_in[2];
    float* out = (float*)d_out;
    float* ws  = (float*)d_ws;

    int ncells  = in_sizes[2];                   // BATCH * S * S = 802816
    int nchunks = (ncells + CPB - 1) / CPB;      // 6272 exactly
    int grid    = GRID < nchunks ? GRID : nchunks;
    // ws usage: GRID * ROW * 4 B = 40 KB; rows [0,grid) all written before read
    yolo_main<<<grid, T, 0, stream>>>(pred, target, choice, ws, ncells, nchunks);
    yolo_reduce<<<1, 256, 0, stream>>>(ws, out, grid);
}

// Round 7
// 192.908 us; speedup vs baseline: 1.0621x; 1.0621x over previous
//
#include <hip/hip_runtime.h>
#include <math.h>

// YOLO loss: pred/target (BATCH,7,7,30) f32, choice (BATCH,7,7) i32
// -> 4 scalars (loc, cls, obj, noobj).
// Round-16: FINAL revert to round-7 (best: 193.9us total, yolo_main ~50us).
// Session closure evidence (rounds 11-15): six structures spanning barrier
// coupling, staging medium (LDS/regs/global_load_lds), prefetch depth,
// occupancy (2-10 streams/CU), and cache policy (L1-bypass nt, L2-bypass
// sc1, full-cache) all converge at 3.7-3.9 TB/s effective read BW:
//   r11 gl_lds+counted-vmcnt: 80us (occupancy crash, phased lockstep)
//   r12/r13 direct gather:    80-84us (VGPR-serialized, line re-touch)
//   r14 wave-private staging: ~53us (no barriers -> no gain)
//   r15 nt+sc1 no-allocate:   ~61us (LOST the ~50% L3 hits; FETCH was
//                             96MB of 196MB logical -> L3 was helping)
// The 6.8 TB/s comparator is a WRITE stream (harness fills); the 6.3 TB/s
// "achievable" figure is a copy (read+write summed). No evidence the read
// path exceeds ~4 TB/s under 50% L3 / 50% HBM mix with 385MB poison-fill
// interference. VALUBusy 10-15%, bank conflicts 0, compute ~6% of budget.
// Verdict: read-path roofline. Remaining bench time = harness fills.
// Structure: persistent blocks + VGPR prefetch (r5) + NON-TEMPORAL
// staging loads (r7: L1-allocation bypass, 75->~50us) + coalesced
// float4->LDS staging (r2) + atomic-free reduction (r3).

typedef float vf4 __attribute__((ext_vector_type(4)));   // nt-load compatible

constexpr int NCH = 30;    // 5*B + C
constexpr int CC  = 20;    // classes
constexpr int ROW = 8;     // floats per block's partial row (32 B)
constexpr int T   = 256;   // threads per block (4 waves)
constexpr int CPB = 128;   // cells per chunk
constexpr int NF4 = CPB * NCH * 2 / 4;  // 1920 vf4 per chunk (pred+target)
constexpr int HF4 = NF4 / 2;            // 960: pred/target boundary
constexpr int GRID = 1280; // 5 blocks/CU * 256 CU

__device__ __forceinline__ void issue_chunk(
    const float* __restrict__ pred, const float* __restrict__ target,
    const int* __restrict__ choice, int cc, int ncells, int tid,
    vf4 (&r)[8], int& ci)
{
    long long base = (long long)cc * CPB;
    if (base + CPB <= (long long)ncells) {
        const vf4* Pb = (const vf4*)(pred + base * NCH);
        const vf4* Tb = (const vf4*)(target + base * NCH);
        #pragma unroll
        for (int j = 0; j < 8; ++j) {
            int k = j * T + tid;            // guards wave-uniform (T mult of 64)
            if (k < NF4)
                r[j] = (k < HF4) ? __builtin_nontemporal_load(&Pb[k])
                                 : __builtin_nontemporal_load(&Tb[k - HF4]);
        }
    } else {
        int nfl = (int)(ncells - base) * NCH;   // valid floats per array
        const float* Pf = pred + base * NCH;
        const float* Tf = target + base * NCH;
        #pragma unroll
        for (int j = 0; j < 8; ++j) {
            int k = j * T + tid;
            vf4 v = (vf4)(0.f, 0.f, 0.f, 0.f);
            if (k < NF4) {
                int kk = (k < HF4) ? k : k - HF4;
                const float* src = (k < HF4) ? Pf : Tf;
                int b = 4 * kk;
                if (b + 0 < nfl) v.x = src[b + 0];
                if (b + 1 < nfl) v.y = src[b + 1];
                if (b + 2 < nfl) v.z = src[b + 2];
                if (b + 3 < nfl) v.w = src[b + 3];
            }
            r[j] = v;
        }
    }
    if (tid < CPB) {
        long long ce = base + tid;
        ci = (ce < (long long)ncells) ? __builtin_nontemporal_load(&choice[ce]) : 0;
    }
}

__global__ __launch_bounds__(T) void yolo_main(
    const float* __restrict__ pred, const float* __restrict__ target,
    const int* __restrict__ choice, float* __restrict__ ws,
    int ncells, int nchunks)
{
    __shared__ float sbuf[2 * CPB * NCH];   // 30720 B: [pred chunk][target chunk]
    const int tid = threadIdx.x;

    float a_loc = 0.f, a_ce = 0.f, a_obj = 0.f, a_no = 0.f;
    float a_nob = 0.f, a_nno = 0.f;

    vf4 r[8];
    int ci = 0;
    int c = blockIdx.x;
    if (c < nchunks) issue_chunk(pred, target, choice, c, ncells, tid, r, ci);

    for (; c < nchunks; c += GRID) {
        __syncthreads();                    // prev compute done reading sbuf
        #pragma unroll
        for (int j = 0; j < 8; ++j) {
            int k = j * T + tid;
            if (k < NF4) *(vf4*)&sbuf[k * 4] = r[j];
        }
        int myc = ci;
        __syncthreads();                    // chunk c visible

        int cn = c + GRID;                  // PREFETCH next chunk before compute
        if (cn < nchunks) issue_chunk(pred, target, choice, cn, ncells, tid, r, ci);

        if (tid < CPB && (long long)c * CPB + tid < ncells) {
            const float* sp  = &sbuf[tid * NCH];
            const float* stt = &sbuf[CPB * NCH + tid * NCH];
            float p[NCH], t[NCH];
            #pragma unroll
            for (int i = 0; i < NCH / 2; ++i) {
                float2 v = *(const float2*)&sp[2 * i];  p[2*i] = v.x; p[2*i+1] = v.y;
            }
            #pragma unroll
            for (int i = 0; i < NCH / 2; ++i) {
                float2 w = *(const float2*)&stt[2 * i]; t[2*i] = w.x; t[2*i+1] = w.y;
            }
            bool csel = myc != 0;

            float tconf = t[4];
            bool  obj = tconf > 0.0f;
            float m = obj ? 1.0f : 0.0f;

            float pxy0 = csel ? p[0] : p[5];
            float pxy1 = csel ? p[1] : p[6];
            float pwh0 = csel ? p[2] : p[7];
            float pwh1 = csel ? p[3] : p[8];
            float pobj = csel ? p[4] : p[9];
            float txy0 = csel ? t[0] : t[5];
            float txy1 = csel ? t[1] : t[6];
            float twh0 = csel ? t[2] : t[7];
            float twh1 = csel ? t[3] : t[8];
            if (!obj) { twh0 = 1.0f; twh1 = 1.0f; }
            float tobj = csel ? tconf : t[9];

            float dx = pxy0 - txy0, dy = pxy1 - txy1;
            float dw = pwh0 - sqrtf(twh0), dh = pwh1 - sqrtf(twh1);
            a_loc += m * (0.5f * (dx*dx + dy*dy) + 0.5f * (dw*dw + dh*dh));

            float dob = pobj - tobj;
            a_obj += m * dob * dob;

            float nm = (tconf == 0.0f) ? 1.0f : 0.0f;
            float d4 = p[4] - tconf, d9 = p[9] - t[9];
            a_no += nm * (d4 * d4 + d9 * d9);

            a_nob += m;
            a_nno += nm;

            int   tcls  = 0;
            float tbest = t[10];
            #pragma unroll
            for (int i = 1; i < CC; ++i) {
                float v = t[10 + i];
                if (v > tbest) { tbest = v; tcls = i; }
            }
            float mx = p[10];
            #pragma unroll
            for (int i = 1; i < CC; ++i) mx = fmaxf(mx, p[10 + i]);
            float e[CC];
            float Z = 0.f;
            #pragma unroll
            for (int i = 0; i < CC; ++i) { e[i] = __expf(p[10+i] - mx); Z += e[i]; }
            float rZ = 1.0f / Z;
            float Z2 = 0.f, sm_t = 0.f;
            #pragma unroll
            for (int i = 0; i < CC; ++i) {
                float sm = e[i] * rZ;          // in (0,1] -> exp safe
                Z2 += __expf(sm);
                if (i == tcls) sm_t = sm;
            }
            a_ce += m * (__logf(Z2) - sm_t);
        }
    }

    // wave(64) shuffle reduction of the 6 accumulators
    #pragma unroll
    for (int off = 32; off > 0; off >>= 1) {
        a_loc += __shfl_down(a_loc, off);
        a_ce  += __shfl_down(a_ce,  off);
        a_obj += __shfl_down(a_obj, off);
        a_no  += __shfl_down(a_no,  off);
        a_nob += __shfl_down(a_nob, off);
        a_nno += __shfl_down(a_nno, off);
    }

    __shared__ float red[4][6];
    int wave = tid >> 6;
    int lane = tid & 63;
    if (lane == 0) {
        red[wave][0] = a_loc; red[wave][1] = a_ce;  red[wave][2] = a_obj;
        red[wave][3] = a_no;  red[wave][4] = a_nob; red[wave][5] = a_nno;
    }
    __syncthreads();
    if (tid < 6) {   // NO atomics: private row per block
        float v = red[0][tid] + red[1][tid] + red[2][tid] + red[3][tid];
        ws[(size_t)blockIdx.x * ROW + tid] = v;
    }
}

__global__ __launch_bounds__(256) void yolo_reduce(
    const float* __restrict__ ws, float* __restrict__ out, int nb)
{
    float s[6] = {0.f, 0.f, 0.f, 0.f, 0.f, 0.f};
    for (int b = threadIdx.x; b < nb; b += 256) {
        #pragma unroll
        for (int j = 0; j < 6; ++j) s[j] += ws[(size_t)b * ROW + j];
    }
    #pragma unroll
    for (int off = 32; off > 0; off >>= 1) {
        #pragma unroll
        for (int j = 0; j < 6; ++j) s[j] += __shfl_down(s[j], off);
    }
    __shared__ float red[4][6];
    int wave = threadIdx.x >> 6;
    int lane = threadIdx.x & 63;
    if (lane == 0) {
        #pragma unroll
        for (int j = 0; j < 6; ++j) red[wave][j] = s[j];
    }
    __syncthreads();
    if (threadIdx.x == 0) {
        float t[6];
        #pragma unroll
        for (int j = 0; j < 6; ++j)
            t[j] = red[0][j] + red[1][j] + red[2][j] + red[3][j];
        out[0] = 5.0f * t[0];                     // loc_loss  (L_COORD = 5)
        out[1] = t[1] / fmaxf(t[4], 1.0f);        // cls_loss
        out[2] = t[2];                            // obj_loss
        out[3] = 0.5f * t[3] / fmaxf(t[5], 1.0f); // noobj_loss (L_NOOBJ = 0.5)
    }
}

extern "C" void kernel_launch(void* const* d_in, const int* in_sizes, int n_in,
                              void* d_out, int out_size, void* d_ws, size_t ws_size,
                              hipStream_t stream) {
    const float* pred   = (const float*)d_in[0];
    const float* target = (const float*)d_in[1];
    const int*   choice = (const int*)d_in[2];
    float* out = (float*)d_out;
    float* ws  = (float*)d_ws;

    int ncells  = in_sizes[2];                   // BATCH * S * S = 802816
    int nchunks = (ncells + CPB - 1) / CPB;      // 6272 exactly
    int grid    = GRID < nchunks ? GRID : nchunks;
    // ws usage: GRID * ROW * 4 B = 40 KB; rows [0,grid) all written before read
    yolo_main<<<grid, T, 0, stream>>>(pred, target, choice, ws, ncells, nchunks);
    yolo_reduce<<<1, 256, 0, stream>>>(ws, out, grid);
}